// Round 16
// baseline (242.108 us; speedup 1.0000x reference)
//
#include <hip/hip_runtime.h>
#include <hip/hip_fp16.h>
#include <math.h>

// ---------------------------------------------------------------------------
// GAT regression: 5x (GATConv -> ReLU -> BN) -> mean pool -> linear head.
// CSR-by-dst built on device each launch (deterministic work).
// R5/R7: LDS bucket-sort CSR build. R8: layer1 algebraic fusion; fp16 features.
// R11: 2 nodes/wave, direct-exp softmax. R14: LDS-staged (s,w) gather.
// R15: layer1 fused into bucket_sort; vectorized transform staging (218us).
// R16: paired gather widened to 4 edge slots x 16B lanes (es=l>>3, cs=l&7):
//      5 serial trips (was 9) per deg~17 node, 2x bytes per load instruction.
// ---------------------------------------------------------------------------

#define CH   4096   // edges per phase-1 chunk
#define BCAP 8192   // per-bucket region capacity in ebuf (mean 4352, ~58 sigma)

// Phase 1: LDS-staged bucketing into fixed-capacity bucket regions.
// Payload: (src<<8) | (dst&255) -- src < 2^24.
__global__ __launch_bounds__(256) void bucket_scatter_kernel(const int* __restrict__ esrc,
                                                             const int* __restrict__ edst,
                                                             int* __restrict__ bkt_cursor,
                                                             unsigned* __restrict__ ebuf,
                                                             int E, int N, int NB) {
    __shared__ unsigned buf[CH];
    __shared__ unsigned short bkt[CH];
    __shared__ int histA[256], base[256], curB[256], gofs[256];
    int t    = threadIdx.x;
    int T    = E + N;
    int c0   = blockIdx.x * CH;
    int cend = min(c0 + CH, T);
    int M    = cend - c0;
    histA[t] = 0;
    __syncthreads();
    for (int i = c0 + t; i < cend; i += 256) {
        int d = (i < E) ? edst[i] : (i - E);
        atomicAdd(&histA[d >> 8], 1);
    }
    __syncthreads();
    int v = histA[t];
    base[t] = v;
    __syncthreads();
    for (int o = 1; o < 256; o <<= 1) {
        int u = (t >= o) ? base[t - o] : 0;
        __syncthreads();
        base[t] += u;
        __syncthreads();
    }
    int excl = base[t] - v;
    __syncthreads();
    base[t] = excl;
    curB[t] = excl;
    __syncthreads();
    if (t < NB && v > 0)
        gofs[t] = t * BCAP + atomicAdd(&bkt_cursor[t], v);
    for (int i = c0 + t; i < cend; i += 256) {
        int s, d;
        if (i < E) { s = esrc[i]; d = edst[i]; }
        else       { s = i - E;   d = s; }       // self loops appended after edges
        int b = d >> 8;
        int r = atomicAdd(&curB[b], 1);
        buf[r] = ((unsigned)s << 8) | (unsigned)(d & 255);
        bkt[r] = (unsigned short)b;
    }
    __syncthreads();
    for (int i = t; i < M; i += 256) {
        int b = bkt[i];
        ebuf[gofs[b] + (i - base[b])] = buf[i];
    }
}

// Phase 2 + fused layer-1: per-bucket counting sort (csr rows land in LDS);
// writes row_start + csr_src; THEN computes layer 1 (rank-1 W1 GAT + bias +
// ReLU + BN) for its 256 nodes straight from csr_lds. One thread per node.
__global__ __launch_bounds__(256) void bucket_sort_kernel(const unsigned* __restrict__ ebuf,
                                                          const int* __restrict__ bkt_cursor,
                                                          int* __restrict__ row_start,
                                                          int* __restrict__ csr_src,
                                                          const float* __restrict__ X,
                                                          const float* __restrict__ W1,
                                                          const float* __restrict__ a_s,
                                                          const float* __restrict__ a_d,
                                                          const float* __restrict__ bias,
                                                          const float* __restrict__ gamma,
                                                          const float* __restrict__ beta,
                                                          const float* __restrict__ mean,
                                                          const float* __restrict__ var,
                                                          __half* __restrict__ xout,
                                                          int N, int NB) {
    __shared__ int cnt[256], ofs[256];
    __shared__ int csr_lds[BCAP];
    __shared__ float wl[64], bsc[64], bsh[64], bbl[64], rbuf[256], dadb[2];
    int t    = threadIdx.x;
    int b    = blockIdx.x;
    int n0   = b << 8;
    int n1   = min(n0 + 256, N);
    int M    = bkt_cursor[b];
    // stage layer-1 channel constants + da/db (wave 0)
    if (t < 64) {
        float w  = W1[t];
        float sc = gamma[t] * rsqrtf(var[t] + 1e-5f);
        wl[t]  = w;
        bsc[t] = sc;
        bsh[t] = beta[t] - mean[t] * sc;
        bbl[t] = bias[t];
        float p1 = w * a_s[t];
        float p2 = w * a_d[t];
#pragma unroll
        for (int o = 32; o > 0; o >>= 1) {
            p1 += __shfl_xor(p1, o, 64);
            p2 += __shfl_xor(p2, o, 64);
        }
        if (t == 0) { dadb[0] = p1; dadb[1] = p2; }
    }
    ofs[t] = (t < b) ? bkt_cursor[t] : 0;
    __syncthreads();
    for (int o = 1; o < 256; o <<= 1) {
        int u = (t >= o) ? ofs[t - o] : 0;
        __syncthreads();
        ofs[t] += u;
        __syncthreads();
    }
    int base = ofs[255];
    __syncthreads();
    const unsigned* reg = ebuf + (size_t)b * BCAP;
    cnt[t] = 0;
    __syncthreads();
    for (int i = t; i < M; i += 256) atomicAdd(&cnt[reg[i] & 255u], 1);
    __syncthreads();
    int v = cnt[t];               // degree of node n0+t
    ofs[t] = v;
    __syncthreads();
    for (int o = 1; o < 256; o <<= 1) {
        int u = (t >= o) ? ofs[t - o] : 0;
        __syncthreads();
        ofs[t] += u;
        __syncthreads();
    }
    int excl = ofs[t] - v;
    if (n0 + t < n1) row_start[n0 + t] = base + excl;
    if (b == NB - 1 && t == 0) row_start[N] = base + M;
    __syncthreads();
    cnt[t] = excl;                // reuse as scatter cursor
    __syncthreads();
    for (int i = t; i < M; i += 256) {
        unsigned e = reg[i];
        int p = atomicAdd(&cnt[e & 255u], 1);
        csr_lds[p] = (int)(e >> 8);
    }
    __syncthreads();
    for (int i = t; i < M; i += 256) csr_src[base + i] = csr_lds[i];
    // ---- fused layer 1: out[d] = BN(ReLU(w * (sum_s alpha_s X[s]) + bias))
    float da = dadb[0], db = dadb[1];
    int d = n0 + t;
    if (d < n1) {
        float add = db * X[d];
        float S = 0.f, z = 0.f;
        for (int j = excl; j < excl + v; ++j) {
            float xs = X[csr_lds[j]];
            float e  = da * xs + add;
            e = (e > 0.f) ? e : 0.2f * e;
            float w = __expf(fminf(e, 60.f));
            z += w;
            S = fmaf(w, xs, S);
        }
        rbuf[t] = S / z;
    }
    __syncthreads();
    // cooperative coalesced output: 4096 uint2 (4 halves) per block
    int nn = n1 - n0;
#pragma unroll
    for (int i = 0; i < 16; ++i) {
        int idx  = (i << 8) + t;
        int nl   = idx >> 4;
        int c4   = (idx & 15) << 2;
        if (nl < nn) {
            float r = rbuf[nl];
            union { __half2 h2[2]; uint2 u; } pk;
            float o0 = fmaxf(fmaf(wl[c4 + 0], r, bbl[c4 + 0]), 0.f);
            float o1 = fmaxf(fmaf(wl[c4 + 1], r, bbl[c4 + 1]), 0.f);
            float o2 = fmaxf(fmaf(wl[c4 + 2], r, bbl[c4 + 2]), 0.f);
            float o3 = fmaxf(fmaf(wl[c4 + 3], r, bbl[c4 + 3]), 0.f);
            pk.h2[0] = __floats2half2_rn(fmaf(o0, bsc[c4 + 0], bsh[c4 + 0]),
                                         fmaf(o1, bsc[c4 + 1], bsh[c4 + 1]));
            pk.h2[1] = __floats2half2_rn(fmaf(o2, bsc[c4 + 2], bsh[c4 + 2]),
                                         fmaf(o3, bsc[c4 + 3], bsh[c4 + 3]));
            *reinterpret_cast<uint2*>(&xout[(size_t)(n0 + nl) * 64 + c4]) = pk.u;
        }
    }
}

// Layers 2..5 transform: register-tiled GEMM; x in fp16, math fp32; h out fp16.
__global__ __launch_bounds__(256) void transform_kernel(const __half* __restrict__ x16,
                                                        const float* __restrict__ W,
                                                        const float* __restrict__ a_s,
                                                        const float* __restrict__ a_d,
                                                        __half* __restrict__ h16,
                                                        float* __restrict__ as,
                                                        float* __restrict__ ad, int N) {
    __shared__ float Wl[64 * 64];
    __shared__ float xT[64 * 68];
    int t    = threadIdx.x;
    int lane = t & 63;
    int base = blockIdx.x * 64;

#pragma unroll
    for (int i = 0; i < 4; ++i) {
        int f4 = (i << 8) + t;     // float4 index 0..1023
        *reinterpret_cast<float4*>(&Wl[f4 << 2]) =
            *reinterpret_cast<const float4*>(&W[f4 << 2]);
    }
#pragma unroll
    for (int i = 0; i < 4; ++i) {
        int idx = (i << 8) + t;    // 0..1023
        int row = idx >> 4;        // node row 0..63
        int c4  = (idx & 15) << 2; // channel 0..60
        int n   = base + row;
        uint2 raw = make_uint2(0u, 0u);
        if (n < N) raw = *reinterpret_cast<const uint2*>(&x16[(size_t)n * 64 + c4]);
        float2 f0 = __half22float2(*reinterpret_cast<__half2*>(&raw.x));
        float2 f1 = __half22float2(*reinterpret_cast<__half2*>(&raw.y));
        xT[(c4 + 0) * 68 + row] = f0.x;
        xT[(c4 + 1) * 68 + row] = f0.y;
        xT[(c4 + 2) * 68 + row] = f1.x;
        xT[(c4 + 3) * 68 + row] = f1.y;
    }
    __syncthreads();

    int c0  = (t & 15) * 4;
    int nl0 = (t >> 4) * 4;
    float acc[4][4] = {{0.f}};
#pragma unroll 8
    for (int k = 0; k < 64; ++k) {
        float4 xv = *reinterpret_cast<const float4*>(&xT[k * 68 + nl0]);
        float4 wlv = *reinterpret_cast<const float4*>(&Wl[k * 64 + c0]);
        acc[0][0] = fmaf(xv.x, wlv.x, acc[0][0]);
        acc[0][1] = fmaf(xv.x, wlv.y, acc[0][1]);
        acc[0][2] = fmaf(xv.x, wlv.z, acc[0][2]);
        acc[0][3] = fmaf(xv.x, wlv.w, acc[0][3]);
        acc[1][0] = fmaf(xv.y, wlv.x, acc[1][0]);
        acc[1][1] = fmaf(xv.y, wlv.y, acc[1][1]);
        acc[1][2] = fmaf(xv.y, wlv.z, acc[1][2]);
        acc[1][3] = fmaf(xv.y, wlv.w, acc[1][3]);
        acc[2][0] = fmaf(xv.z, wlv.x, acc[2][0]);
        acc[2][1] = fmaf(xv.z, wlv.y, acc[2][1]);
        acc[2][2] = fmaf(xv.z, wlv.z, acc[2][2]);
        acc[2][3] = fmaf(xv.z, wlv.w, acc[2][3]);
        acc[3][0] = fmaf(xv.w, wlv.x, acc[3][0]);
        acc[3][1] = fmaf(xv.w, wlv.y, acc[3][1]);
        acc[3][2] = fmaf(xv.w, wlv.z, acc[3][2]);
        acc[3][3] = fmaf(xv.w, wlv.w, acc[3][3]);
    }

    float4 asv = *reinterpret_cast<const float4*>(&a_s[c0]);
    float4 adv = *reinterpret_cast<const float4*>(&a_d[c0]);
#pragma unroll
    for (int i = 0; i < 4; ++i) {
        int n = base + nl0 + i;
        if (n < N) {
            union { __half2 h2[2]; uint2 u; } pk;
            pk.h2[0] = __floats2half2_rn(acc[i][0], acc[i][1]);
            pk.h2[1] = __floats2half2_rn(acc[i][2], acc[i][3]);
            *reinterpret_cast<uint2*>(&h16[(size_t)n * 64 + c0]) = pk.u;
        }
        float s1 = acc[i][0] * asv.x + acc[i][1] * asv.y + acc[i][2] * asv.z + acc[i][3] * asv.w;
        float s2 = acc[i][0] * adv.x + acc[i][1] * adv.y + acc[i][2] * adv.z + acc[i][3] * adv.w;
#pragma unroll
        for (int o = 8; o > 0; o >>= 1) {
            s1 += __shfl_xor(s1, o, 64);
            s2 += __shfl_xor(s2, o, 64);
        }
        if ((lane & 15) == 0 && n < N) { as[n] = s1; ad[n] = s2; }
    }
}

// R16 aggregate layers 2..5: TWO nodes per wave. Direct-exp softmax (phase 1,
// lane=edge; (s,w) staged in per-wave LDS). Phase 2 gather: 4 edge slots x
// 8 lanes x 16B (es=l>>3, cs=l&7 -> channels [cs*8, cs*8+8)); one ds_read_b64
// broadcast + one uint4 h-load per trip; fold via shfl_xor(8,16). Lanes >= deg
// staged (s=0,w=0) so no guard needed (contribute 0).
__global__ __launch_bounds__(256) void aggregate_kernel(const __half* __restrict__ h16,
                                                        const float* __restrict__ as,
                                                        const float* __restrict__ ad,
                                                        const int* __restrict__ row_start,
                                                        const int* __restrict__ csr_src,
                                                        const float* __restrict__ bias,
                                                        const float* __restrict__ gamma,
                                                        const float* __restrict__ beta,
                                                        const float* __restrict__ mean,
                                                        const float* __restrict__ var,
                                                        __half* __restrict__ xout, int N) {
    __shared__ float2 swbuf[4][64];
    int lane = threadIdx.x & 63;
    int wave = threadIdx.x >> 6;
    int wpb  = blockDim.x >> 6;
    int half = lane >> 5;
    int l    = lane & 31;
    int P = (N + 1) >> 1;
    for (int p = blockIdx.x * wpb + wave; p < P; p += gridDim.x * wpb) {
        int d0  = p << 1;
        int d1  = d0 + 1;
        int rs0 = row_start[d0];
        int re0 = row_start[d0 + 1];
        int deg0 = re0 - rs0;
        int deg1 = -1, re1 = 0;
        if (d1 < N) { re1 = row_start[d1 + 1]; deg1 = re1 - re0; }
        if (deg0 <= 32 && deg1 >= 0 && deg1 <= 32) {
            // ---- paired fast path ----
            int d   = half ? d1 : d0;
            int rs  = half ? re0 : rs0;
            int deg = half ? deg1 : deg0;
            float add = ad[d];
            int s = 0; float w = 0.f;
            if (l < deg) {
                s = csr_src[rs + l];
                float e = as[s] + add;
                e = (e > 0.f) ? e : 0.2f * e;
                w = __expf(fminf(e, 60.f));
            }
            swbuf[wave][lane] = make_float2(__int_as_float(s), w);
            float z = w;
#pragma unroll
            for (int o = 16; o > 0; o >>= 1) z += __shfl_xor(z, o, 64);
            asm volatile("s_waitcnt lgkmcnt(0)" ::: "memory");
            int es = l >> 3;            // edge slot 0..3
            int c8 = (l & 7) << 3;      // channel base (8 channels, 16B)
            float a0 = 0.f, a1 = 0.f, a2 = 0.f, a3 = 0.f;
            float a4 = 0.f, a5 = 0.f, a6 = 0.f, a7 = 0.f;
            int nb = (deg + 3) >> 2;
#pragma unroll 2
            for (int b = 0; b < nb; ++b) {
                int j  = (b << 2) + es;                    // < 32 always
                float2 sw = swbuf[wave][(half << 5) + j];  // 8-lane uniform -> bcast
                int   sj = __float_as_int(sw.x);
                float wj = sw.y;
                union { uint4 u; __half2 h2[4]; } raw;
                raw.u = *reinterpret_cast<const uint4*>(h16 + (size_t)sj * 64 + c8);
                float2 f0 = __half22float2(raw.h2[0]);
                float2 f1 = __half22float2(raw.h2[1]);
                float2 f2 = __half22float2(raw.h2[2]);
                float2 f3 = __half22float2(raw.h2[3]);
                a0 = fmaf(f0.x, wj, a0); a1 = fmaf(f0.y, wj, a1);
                a2 = fmaf(f1.x, wj, a2); a3 = fmaf(f1.y, wj, a3);
                a4 = fmaf(f2.x, wj, a4); a5 = fmaf(f2.y, wj, a5);
                a6 = fmaf(f3.x, wj, a6); a7 = fmaf(f3.y, wj, a7);
            }
            a0 += __shfl_xor(a0, 8, 64); a0 += __shfl_xor(a0, 16, 64);
            a1 += __shfl_xor(a1, 8, 64); a1 += __shfl_xor(a1, 16, 64);
            a2 += __shfl_xor(a2, 8, 64); a2 += __shfl_xor(a2, 16, 64);
            a3 += __shfl_xor(a3, 8, 64); a3 += __shfl_xor(a3, 16, 64);
            a4 += __shfl_xor(a4, 8, 64); a4 += __shfl_xor(a4, 16, 64);
            a5 += __shfl_xor(a5, 8, 64); a5 += __shfl_xor(a5, 16, 64);
            a6 += __shfl_xor(a6, 8, 64); a6 += __shfl_xor(a6, 16, 64);
            a7 += __shfl_xor(a7, 8, 64); a7 += __shfl_xor(a7, 16, 64);
            if (es == 0) {   // 8 lanes per half, channels [c8, c8+8)
                float4 bc0 = *reinterpret_cast<const float4*>(&bias[c8]);
                float4 bc1 = *reinterpret_cast<const float4*>(&bias[c8 + 4]);
                float4 ga0 = *reinterpret_cast<const float4*>(&gamma[c8]);
                float4 ga1 = *reinterpret_cast<const float4*>(&gamma[c8 + 4]);
                float4 be0 = *reinterpret_cast<const float4*>(&beta[c8]);
                float4 be1 = *reinterpret_cast<const float4*>(&beta[c8 + 4]);
                float4 mn0 = *reinterpret_cast<const float4*>(&mean[c8]);
                float4 mn1 = *reinterpret_cast<const float4*>(&mean[c8 + 4]);
                float4 vr0 = *reinterpret_cast<const float4*>(&var[c8]);
                float4 vr1 = *reinterpret_cast<const float4*>(&var[c8 + 4]);
                float rz = 1.f / z;
                float o0 = fmaxf(fmaf(a0, rz, bc0.x), 0.f);
                float o1 = fmaxf(fmaf(a1, rz, bc0.y), 0.f);
                float o2 = fmaxf(fmaf(a2, rz, bc0.z), 0.f);
                float o3 = fmaxf(fmaf(a3, rz, bc0.w), 0.f);
                float o4 = fmaxf(fmaf(a4, rz, bc1.x), 0.f);
                float o5 = fmaxf(fmaf(a5, rz, bc1.y), 0.f);
                float o6 = fmaxf(fmaf(a6, rz, bc1.z), 0.f);
                float o7 = fmaxf(fmaf(a7, rz, bc1.w), 0.f);
                float s0 = ga0.x * rsqrtf(vr0.x + 1e-5f);
                float s1 = ga0.y * rsqrtf(vr0.y + 1e-5f);
                float s2 = ga0.z * rsqrtf(vr0.z + 1e-5f);
                float s3 = ga0.w * rsqrtf(vr0.w + 1e-5f);
                float s4 = ga1.x * rsqrtf(vr1.x + 1e-5f);
                float s5 = ga1.y * rsqrtf(vr1.y + 1e-5f);
                float s6 = ga1.z * rsqrtf(vr1.z + 1e-5f);
                float s7 = ga1.w * rsqrtf(vr1.w + 1e-5f);
                union { __half2 h2[4]; uint4 u; } pk;
                pk.h2[0] = __floats2half2_rn(fmaf(o0, s0, be0.x - mn0.x * s0),
                                             fmaf(o1, s1, be0.y - mn0.y * s1));
                pk.h2[1] = __floats2half2_rn(fmaf(o2, s2, be0.z - mn0.z * s2),
                                             fmaf(o3, s3, be0.w - mn0.w * s3));
                pk.h2[2] = __floats2half2_rn(fmaf(o4, s4, be1.x - mn1.x * s4),
                                             fmaf(o5, s5, be1.y - mn1.y * s5));
                pk.h2[3] = __floats2half2_rn(fmaf(o6, s6, be1.z - mn1.z * s6),
                                             fmaf(o7, s7, be1.w - mn1.w * s7));
                *reinterpret_cast<uint4*>(&xout[(size_t)d * 64 + c8]) = pk.u;
            }
        } else {
            // ---- per-node paths (rare) ----
            for (int k = 0; k < 2; ++k) {
                int d = d0 + k;
                if (d >= N) break;
                int rs  = row_start[d], re = row_start[d + 1];
                int deg = re - rs;
                float add = ad[d];
                int cg = (lane & 15) << 2;
                float4 bcv = *reinterpret_cast<const float4*>(&bias[cg]);
                float4 gav = *reinterpret_cast<const float4*>(&gamma[cg]);
                float4 bev = *reinterpret_cast<const float4*>(&beta[cg]);
                float4 mnv = *reinterpret_cast<const float4*>(&mean[cg]);
                float4 vrv = *reinterpret_cast<const float4*>(&var[cg]);
                float sc0 = gav.x * rsqrtf(vrv.x + 1e-5f), sh0 = bev.x - mnv.x * sc0;
                float sc1 = gav.y * rsqrtf(vrv.y + 1e-5f), sh1 = bev.y - mnv.y * sc1;
                float sc2 = gav.z * rsqrtf(vrv.z + 1e-5f), sh2 = bev.z - mnv.z * sc2;
                float sc3 = gav.w * rsqrtf(vrv.w + 1e-5f), sh3 = bev.w - mnv.w * sc3;
                if (deg <= 64) {
                    int s = 0; float w = 0.f;
                    if (lane < deg) {
                        s = csr_src[rs + lane];
                        float e = as[s] + add;
                        e = (e > 0.f) ? e : 0.2f * e;
                        w = __expf(fminf(e, 60.f));
                    }
                    float z = w;
#pragma unroll
                    for (int o = 32; o > 0; o >>= 1) z += __shfl_xor(z, o, 64);
                    int es4 = lane >> 4;
                    float a0 = 0.f, a1 = 0.f, a2 = 0.f, a3 = 0.f;
                    int nb = (deg + 3) >> 2;
                    for (int b = 0; b < nb; ++b) {
                        int j = (b << 2) + es4;
                        int   sj = __shfl(s, j, 64);
                        float wj = __shfl(w, j, 64);
                        const __half2* hp = reinterpret_cast<const __half2*>(h16 + (size_t)sj * 64 + cg);
                        float2 f0 = __half22float2(hp[0]);
                        float2 f1 = __half22float2(hp[1]);
                        a0 = fmaf(f0.x, wj, a0);
                        a1 = fmaf(f0.y, wj, a1);
                        a2 = fmaf(f1.x, wj, a2);
                        a3 = fmaf(f1.y, wj, a3);
                    }
                    a0 += __shfl_xor(a0, 16, 64); a0 += __shfl_xor(a0, 32, 64);
                    a1 += __shfl_xor(a1, 16, 64); a1 += __shfl_xor(a1, 32, 64);
                    a2 += __shfl_xor(a2, 16, 64); a2 += __shfl_xor(a2, 32, 64);
                    a3 += __shfl_xor(a3, 16, 64); a3 += __shfl_xor(a3, 32, 64);
                    if (lane < 16) {
                        float rz = 1.f / z;
                        float o0 = fmaxf(fmaf(a0, rz, bcv.x), 0.f);
                        float o1 = fmaxf(fmaf(a1, rz, bcv.y), 0.f);
                        float o2 = fmaxf(fmaf(a2, rz, bcv.z), 0.f);
                        float o3 = fmaxf(fmaf(a3, rz, bcv.w), 0.f);
                        union { __half2 h2[2]; uint2 u; } pk;
                        pk.h2[0] = __floats2half2_rn(fmaf(o0, sc0, sh0), fmaf(o1, sc1, sh1));
                        pk.h2[1] = __floats2half2_rn(fmaf(o2, sc2, sh2), fmaf(o3, sc3, sh3));
                        *reinterpret_cast<uint2*>(&xout[(size_t)d * 64 + cg]) = pk.u;
                    }
                } else {  // deg > 64: serial, lane = channel
                    float z = 0.f;
                    for (int j = rs + lane; j < re; j += 64) {
                        float e = as[csr_src[j]] + add;
                        e = (e > 0.f) ? e : 0.2f * e;
                        z += __expf(fminf(e, 60.f));
                    }
#pragma unroll
                    for (int o = 32; o > 0; o >>= 1) z += __shfl_xor(z, o, 64);
                    float acc = 0.f;
                    for (int j = rs; j < re; ++j) {
                        int si = csr_src[j];
                        float e = as[si] + add;
                        e = (e > 0.f) ? e : 0.2f * e;
                        float w = __expf(fminf(e, 60.f));
                        acc = fmaf(__half2float(h16[(size_t)si * 64 + lane]), w, acc);
                    }
                    float scl = gamma[lane] * rsqrtf(var[lane] + 1e-5f);
                    float shf = beta[lane] - mean[lane] * scl;
                    float o = fmaxf(acc / z + bias[lane], 0.f);
                    xout[(size_t)d * 64 + lane] = __float2half(fmaf(o, scl, shf));
                }
            }
        }
    }
}

// Pool: block g binary-searches sorted batch for its node range; x is fp16.
__global__ __launch_bounds__(256) void pool_kernel(const __half* __restrict__ x16,
                                                   const int* __restrict__ batch,
                                                   const float* __restrict__ Wr,
                                                   const float* __restrict__ br,
                                                   float* __restrict__ out, int N, int G) {
    __shared__ float wsum[4][64];
    __shared__ int bounds[2];
    int t    = threadIdx.x;
    int lane = t & 63;
    int wv   = t >> 6;
    int g    = blockIdx.x;
    if (g >= G) return;
    if (t < 2) {
        int key = g + t;         // lower_bound(batch, key)
        int lo = 0, hi = N;
        while (lo < hi) {
            int mid = (lo + hi) >> 1;
            if (batch[mid] < key) lo = mid + 1; else hi = mid;
        }
        bounds[t] = lo;
    }
    __syncthreads();
    int s   = bounds[0];
    int cnt = bounds[1] - s;
    float a0 = 0.f, a1 = 0.f, a2 = 0.f, a3 = 0.f;
    for (int r = wv * 4; r < cnt; r += 16) {
        const __half* row = x16 + (size_t)(s + r) * 64 + lane;
        a0 += __half2float(row[0]);
        if (r + 1 < cnt) a1 += __half2float(row[64]);
        if (r + 2 < cnt) a2 += __half2float(row[128]);
        if (r + 3 < cnt) a3 += __half2float(row[192]);
    }
    wsum[wv][lane] = (a0 + a1) + (a2 + a3);
    __syncthreads();
    if (wv == 0) {
        float tot = (wsum[0][lane] + wsum[1][lane]) + (wsum[2][lane] + wsum[3][lane]);
        float pooled = tot / fmaxf((float)cnt, 1.f);
        out[G + (size_t)g * 64 + lane] = pooled;
        float p = pooled * Wr[lane];
#pragma unroll
        for (int o = 32; o > 0; o >>= 1) p += __shfl_xor(p, o, 64);
        if (lane == 0) out[g] = p + br[0];
    }
}

extern "C" void kernel_launch(void* const* d_in, const int* in_sizes, int n_in,
                              void* d_out, int out_size, void* d_ws, size_t ws_size,
                              hipStream_t stream) {
    const float* X        = (const float*)d_in[0];
    const int*   ei       = (const int*)d_in[1];
    const int*   batch    = (const int*)d_in[2];
    const float* W1       = (const float*)d_in[3];
    const float* Ws       = (const float*)d_in[4];
    const float* att_src  = (const float*)d_in[5];
    const float* att_dst  = (const float*)d_in[6];
    const float* bias     = (const float*)d_in[7];
    const float* bn_gamma = (const float*)d_in[8];
    const float* bn_beta  = (const float*)d_in[9];
    const float* bn_mean  = (const float*)d_in[10];
    const float* bn_var   = (const float*)d_in[11];
    const float* Wr       = (const float*)d_in[12];
    const float* br       = (const float*)d_in[13];

    const int N = in_sizes[0];        // IN == 1
    const int E = in_sizes[1] / 2;
    const int G = out_size / 65;      // pred[G] + pooled[G*64]
    const int T = E + N;
    const int NB = (N + 255) >> 8;    // dst buckets (196 for N=50000; <=256)

    char* ws = (char*)d_ws;
    size_t off = 0;
    auto take = [&](size_t bytes) {
        void* p = ws + off;
        off = (off + bytes + 255) & ~(size_t)255;
        return p;
    };
    int*      row_start  = (int*)take(sizeof(int) * (N + 1));
    int*      csr_src    = (int*)take(sizeof(int) * T);
    float*    as         = (float*)take(sizeof(float) * N);
    float*    ad         = (float*)take(sizeof(float) * N);
    __half*   h16        = (__half*)take(sizeof(__half) * (size_t)N * 64);
    __half*   xa         = (__half*)take(sizeof(__half) * (size_t)N * 64);
    __half*   xb         = (__half*)take(sizeof(__half) * (size_t)N * 64);
    int*      bkt_cursor = (int*)take(sizeof(int) * NB);
    unsigned* ebuf       = (unsigned*)take(sizeof(unsigned) * (size_t)NB * BCAP);
    (void)ws_size;

    const int* esrc = ei;
    const int* edst = ei + E;

    hipMemsetAsync(bkt_cursor, 0, sizeof(int) * NB, stream);

    bucket_scatter_kernel<<<(T + CH - 1) / CH, 256, 0, stream>>>(esrc, edst, bkt_cursor,
                                                                 ebuf, E, N, NB);
    bucket_sort_kernel<<<NB, 256, 0, stream>>>(ebuf, bkt_cursor, row_start, csr_src,
                                               X, W1, att_src, att_dst,
                                               bias, bn_gamma, bn_beta, bn_mean, bn_var,
                                               xa, N, NB);

    int tb   = (N + 63) / 64;           // transform: 64-node tiles
    int P    = (N + 1) / 2;
    int wb2  = (P + 3) / 4;             // aggregate: 2 nodes/wave
    __half* xin = xa;
    __half* xout = xb;
    for (int L = 1; L < 5; ++L) {
        transform_kernel<<<tb, 256, 0, stream>>>(xin, Ws + (size_t)(L - 1) * 64 * 64,
                                                 att_src + (size_t)L * 64, att_dst + (size_t)L * 64,
                                                 h16, as, ad, N);
        aggregate_kernel<<<wb2, 256, 0, stream>>>(h16, as, ad, row_start, csr_src,
                                                  bias + (size_t)L * 64, bn_gamma + (size_t)L * 64,
                                                  bn_beta + (size_t)L * 64, bn_mean + (size_t)L * 64,
                                                  bn_var + (size_t)L * 64, xout, N);
        __half* t = xin; xin = xout; xout = t;
    }

    pool_kernel<<<G, 256, 0, stream>>>(xin, batch, Wr, br, (float*)d_out, N, G);
}

// Round 17
// 217.069 us; speedup vs baseline: 1.1154x; 1.1154x over previous
//
#include <hip/hip_runtime.h>
#include <hip/hip_fp16.h>
#include <math.h>

// ---------------------------------------------------------------------------
// GAT regression: 5x (GATConv -> ReLU -> BN) -> mean pool -> linear head.
// CSR-by-dst built on device each launch (deterministic work).
// R5/R7: LDS bucket-sort CSR build. R8: layer1 algebraic fusion; fp16 features.
// R11: 2 nodes/wave, direct-exp softmax. R14: LDS-staged (s,w) gather.
// R15: layer-1 aggregate fused INTO bucket_sort; vectorized transform staging.
// R17: revert R16 wide-slot gather (regressed 218->242); R15 is the optimum:
//      aggregate runs at ~5.5 TB/s effective random-gather (near 6.3 TB/s
//      streaming ceiling) -- 4 alternative shapes all regressed or neutral.
// ---------------------------------------------------------------------------

#define CH   4096   // edges per phase-1 chunk
#define BCAP 8192   // per-bucket region capacity in ebuf (mean 4352, ~58 sigma)

// Phase 1: LDS-staged bucketing into fixed-capacity bucket regions.
// Payload: (src<<8) | (dst&255) -- src < 2^24.
__global__ __launch_bounds__(256) void bucket_scatter_kernel(const int* __restrict__ esrc,
                                                             const int* __restrict__ edst,
                                                             int* __restrict__ bkt_cursor,
                                                             unsigned* __restrict__ ebuf,
                                                             int E, int N, int NB) {
    __shared__ unsigned buf[CH];
    __shared__ unsigned short bkt[CH];
    __shared__ int histA[256], base[256], curB[256], gofs[256];
    int t    = threadIdx.x;
    int T    = E + N;
    int c0   = blockIdx.x * CH;
    int cend = min(c0 + CH, T);
    int M    = cend - c0;
    histA[t] = 0;
    __syncthreads();
    for (int i = c0 + t; i < cend; i += 256) {
        int d = (i < E) ? edst[i] : (i - E);
        atomicAdd(&histA[d >> 8], 1);
    }
    __syncthreads();
    int v = histA[t];
    base[t] = v;
    __syncthreads();
    for (int o = 1; o < 256; o <<= 1) {
        int u = (t >= o) ? base[t - o] : 0;
        __syncthreads();
        base[t] += u;
        __syncthreads();
    }
    int excl = base[t] - v;
    __syncthreads();
    base[t] = excl;
    curB[t] = excl;
    __syncthreads();
    if (t < NB && v > 0)
        gofs[t] = t * BCAP + atomicAdd(&bkt_cursor[t], v);
    for (int i = c0 + t; i < cend; i += 256) {
        int s, d;
        if (i < E) { s = esrc[i]; d = edst[i]; }
        else       { s = i - E;   d = s; }       // self loops appended after edges
        int b = d >> 8;
        int r = atomicAdd(&curB[b], 1);
        buf[r] = ((unsigned)s << 8) | (unsigned)(d & 255);
        bkt[r] = (unsigned short)b;
    }
    __syncthreads();
    for (int i = t; i < M; i += 256) {
        int b = bkt[i];
        ebuf[gofs[b] + (i - base[b])] = buf[i];
    }
}

// Phase 2 + fused layer-1: per-bucket counting sort (csr rows land in LDS);
// writes row_start + csr_src; THEN computes layer 1 (rank-1 W1 GAT + bias +
// ReLU + BN) for its 256 nodes straight from csr_lds. One thread per node.
__global__ __launch_bounds__(256) void bucket_sort_kernel(const unsigned* __restrict__ ebuf,
                                                          const int* __restrict__ bkt_cursor,
                                                          int* __restrict__ row_start,
                                                          int* __restrict__ csr_src,
                                                          const float* __restrict__ X,
                                                          const float* __restrict__ W1,
                                                          const float* __restrict__ a_s,
                                                          const float* __restrict__ a_d,
                                                          const float* __restrict__ bias,
                                                          const float* __restrict__ gamma,
                                                          const float* __restrict__ beta,
                                                          const float* __restrict__ mean,
                                                          const float* __restrict__ var,
                                                          __half* __restrict__ xout,
                                                          int N, int NB) {
    __shared__ int cnt[256], ofs[256];
    __shared__ int csr_lds[BCAP];
    __shared__ float wl[64], bsc[64], bsh[64], bbl[64], rbuf[256], dadb[2];
    int t    = threadIdx.x;
    int b    = blockIdx.x;
    int n0   = b << 8;
    int n1   = min(n0 + 256, N);
    int M    = bkt_cursor[b];
    // stage layer-1 channel constants + da/db (wave 0)
    if (t < 64) {
        float w  = W1[t];
        float sc = gamma[t] * rsqrtf(var[t] + 1e-5f);
        wl[t]  = w;
        bsc[t] = sc;
        bsh[t] = beta[t] - mean[t] * sc;
        bbl[t] = bias[t];
        float p1 = w * a_s[t];
        float p2 = w * a_d[t];
#pragma unroll
        for (int o = 32; o > 0; o >>= 1) {
            p1 += __shfl_xor(p1, o, 64);
            p2 += __shfl_xor(p2, o, 64);
        }
        if (t == 0) { dadb[0] = p1; dadb[1] = p2; }
    }
    ofs[t] = (t < b) ? bkt_cursor[t] : 0;
    __syncthreads();
    for (int o = 1; o < 256; o <<= 1) {
        int u = (t >= o) ? ofs[t - o] : 0;
        __syncthreads();
        ofs[t] += u;
        __syncthreads();
    }
    int base = ofs[255];
    __syncthreads();
    const unsigned* reg = ebuf + (size_t)b * BCAP;
    cnt[t] = 0;
    __syncthreads();
    for (int i = t; i < M; i += 256) atomicAdd(&cnt[reg[i] & 255u], 1);
    __syncthreads();
    int v = cnt[t];               // degree of node n0+t
    ofs[t] = v;
    __syncthreads();
    for (int o = 1; o < 256; o <<= 1) {
        int u = (t >= o) ? ofs[t - o] : 0;
        __syncthreads();
        ofs[t] += u;
        __syncthreads();
    }
    int excl = ofs[t] - v;
    if (n0 + t < n1) row_start[n0 + t] = base + excl;
    if (b == NB - 1 && t == 0) row_start[N] = base + M;
    __syncthreads();
    cnt[t] = excl;                // reuse as scatter cursor
    __syncthreads();
    for (int i = t; i < M; i += 256) {
        unsigned e = reg[i];
        int p = atomicAdd(&cnt[e & 255u], 1);
        csr_lds[p] = (int)(e >> 8);
    }
    __syncthreads();
    for (int i = t; i < M; i += 256) csr_src[base + i] = csr_lds[i];
    // ---- fused layer 1: out[d] = BN(ReLU(w * (sum_s alpha_s X[s]) + bias))
    float da = dadb[0], db = dadb[1];
    int d = n0 + t;
    if (d < n1) {
        float add = db * X[d];
        float S = 0.f, z = 0.f;
        for (int j = excl; j < excl + v; ++j) {
            float xs = X[csr_lds[j]];
            float e  = da * xs + add;
            e = (e > 0.f) ? e : 0.2f * e;
            float w = __expf(fminf(e, 60.f));
            z += w;
            S = fmaf(w, xs, S);
        }
        rbuf[t] = S / z;
    }
    __syncthreads();
    // cooperative coalesced output: 4096 uint2 (4 halves) per block
    int nn = n1 - n0;
#pragma unroll
    for (int i = 0; i < 16; ++i) {
        int idx  = (i << 8) + t;
        int nl   = idx >> 4;
        int c4   = (idx & 15) << 2;
        if (nl < nn) {
            float r = rbuf[nl];
            union { __half2 h2[2]; uint2 u; } pk;
            float o0 = fmaxf(fmaf(wl[c4 + 0], r, bbl[c4 + 0]), 0.f);
            float o1 = fmaxf(fmaf(wl[c4 + 1], r, bbl[c4 + 1]), 0.f);
            float o2 = fmaxf(fmaf(wl[c4 + 2], r, bbl[c4 + 2]), 0.f);
            float o3 = fmaxf(fmaf(wl[c4 + 3], r, bbl[c4 + 3]), 0.f);
            pk.h2[0] = __floats2half2_rn(fmaf(o0, bsc[c4 + 0], bsh[c4 + 0]),
                                         fmaf(o1, bsc[c4 + 1], bsh[c4 + 1]));
            pk.h2[1] = __floats2half2_rn(fmaf(o2, bsc[c4 + 2], bsh[c4 + 2]),
                                         fmaf(o3, bsc[c4 + 3], bsh[c4 + 3]));
            *reinterpret_cast<uint2*>(&xout[(size_t)(n0 + nl) * 64 + c4]) = pk.u;
        }
    }
}

// Layers 2..5 transform: register-tiled GEMM; x in fp16, math fp32; h out fp16.
__global__ __launch_bounds__(256) void transform_kernel(const __half* __restrict__ x16,
                                                        const float* __restrict__ W,
                                                        const float* __restrict__ a_s,
                                                        const float* __restrict__ a_d,
                                                        __half* __restrict__ h16,
                                                        float* __restrict__ as,
                                                        float* __restrict__ ad, int N) {
    __shared__ float Wl[64 * 64];
    __shared__ float xT[64 * 68];
    int t    = threadIdx.x;
    int lane = t & 63;
    int base = blockIdx.x * 64;

#pragma unroll
    for (int i = 0; i < 4; ++i) {
        int f4 = (i << 8) + t;     // float4 index 0..1023
        *reinterpret_cast<float4*>(&Wl[f4 << 2]) =
            *reinterpret_cast<const float4*>(&W[f4 << 2]);
    }
#pragma unroll
    for (int i = 0; i < 4; ++i) {
        int idx = (i << 8) + t;    // 0..1023
        int row = idx >> 4;        // node row 0..63
        int c4  = (idx & 15) << 2; // channel 0..60
        int n   = base + row;
        uint2 raw = make_uint2(0u, 0u);
        if (n < N) raw = *reinterpret_cast<const uint2*>(&x16[(size_t)n * 64 + c4]);
        float2 f0 = __half22float2(*reinterpret_cast<__half2*>(&raw.x));
        float2 f1 = __half22float2(*reinterpret_cast<__half2*>(&raw.y));
        xT[(c4 + 0) * 68 + row] = f0.x;
        xT[(c4 + 1) * 68 + row] = f0.y;
        xT[(c4 + 2) * 68 + row] = f1.x;
        xT[(c4 + 3) * 68 + row] = f1.y;
    }
    __syncthreads();

    int c0  = (t & 15) * 4;
    int nl0 = (t >> 4) * 4;
    float acc[4][4] = {{0.f}};
#pragma unroll 8
    for (int k = 0; k < 64; ++k) {
        float4 xv = *reinterpret_cast<const float4*>(&xT[k * 68 + nl0]);
        float4 wlv = *reinterpret_cast<const float4*>(&Wl[k * 64 + c0]);
        acc[0][0] = fmaf(xv.x, wlv.x, acc[0][0]);
        acc[0][1] = fmaf(xv.x, wlv.y, acc[0][1]);
        acc[0][2] = fmaf(xv.x, wlv.z, acc[0][2]);
        acc[0][3] = fmaf(xv.x, wlv.w, acc[0][3]);
        acc[1][0] = fmaf(xv.y, wlv.x, acc[1][0]);
        acc[1][1] = fmaf(xv.y, wlv.y, acc[1][1]);
        acc[1][2] = fmaf(xv.y, wlv.z, acc[1][2]);
        acc[1][3] = fmaf(xv.y, wlv.w, acc[1][3]);
        acc[2][0] = fmaf(xv.z, wlv.x, acc[2][0]);
        acc[2][1] = fmaf(xv.z, wlv.y, acc[2][1]);
        acc[2][2] = fmaf(xv.z, wlv.z, acc[2][2]);
        acc[2][3] = fmaf(xv.z, wlv.w, acc[2][3]);
        acc[3][0] = fmaf(xv.w, wlv.x, acc[3][0]);
        acc[3][1] = fmaf(xv.w, wlv.y, acc[3][1]);
        acc[3][2] = fmaf(xv.w, wlv.z, acc[3][2]);
        acc[3][3] = fmaf(xv.w, wlv.w, acc[3][3]);
    }

    float4 asv = *reinterpret_cast<const float4*>(&a_s[c0]);
    float4 adv = *reinterpret_cast<const float4*>(&a_d[c0]);
#pragma unroll
    for (int i = 0; i < 4; ++i) {
        int n = base + nl0 + i;
        if (n < N) {
            union { __half2 h2[2]; uint2 u; } pk;
            pk.h2[0] = __floats2half2_rn(acc[i][0], acc[i][1]);
            pk.h2[1] = __floats2half2_rn(acc[i][2], acc[i][3]);
            *reinterpret_cast<uint2*>(&h16[(size_t)n * 64 + c0]) = pk.u;
        }
        float s1 = acc[i][0] * asv.x + acc[i][1] * asv.y + acc[i][2] * asv.z + acc[i][3] * asv.w;
        float s2 = acc[i][0] * adv.x + acc[i][1] * adv.y + acc[i][2] * adv.z + acc[i][3] * adv.w;
#pragma unroll
        for (int o = 8; o > 0; o >>= 1) {
            s1 += __shfl_xor(s1, o, 64);
            s2 += __shfl_xor(s2, o, 64);
        }
        if ((lane & 15) == 0 && n < N) { as[n] = s1; ad[n] = s2; }
    }
}

// R14 aggregate layers 2..5: TWO nodes per wave (32-lane halves). Direct-exp
// softmax (phase 1, lane=edge). Phase 2 gather: (s,w) staged in per-wave LDS
// (one ds_write_b64), each trip does ONE ds_read_b64 broadcast (16-lane
// uniform addr) + one 8B h16 load; fold via shfl_xor(16).
__global__ __launch_bounds__(256) void aggregate_kernel(const __half* __restrict__ h16,
                                                        const float* __restrict__ as,
                                                        const float* __restrict__ ad,
                                                        const int* __restrict__ row_start,
                                                        const int* __restrict__ csr_src,
                                                        const float* __restrict__ bias,
                                                        const float* __restrict__ gamma,
                                                        const float* __restrict__ beta,
                                                        const float* __restrict__ mean,
                                                        const float* __restrict__ var,
                                                        __half* __restrict__ xout, int N) {
    __shared__ float2 swbuf[4][64];
    int lane = threadIdx.x & 63;
    int wave = threadIdx.x >> 6;
    int wpb  = blockDim.x >> 6;
    int half = lane >> 5;
    int l    = lane & 31;
    int cg   = (l & 15) << 2;   // 4-channel group (paired + single paths)
    float4 bcv = *reinterpret_cast<const float4*>(&bias[cg]);
    float4 gav = *reinterpret_cast<const float4*>(&gamma[cg]);
    float4 bev = *reinterpret_cast<const float4*>(&beta[cg]);
    float4 mnv = *reinterpret_cast<const float4*>(&mean[cg]);
    float4 vrv = *reinterpret_cast<const float4*>(&var[cg]);
    float sc0 = gav.x * rsqrtf(vrv.x + 1e-5f), sh0 = bev.x - mnv.x * sc0;
    float sc1 = gav.y * rsqrtf(vrv.y + 1e-5f), sh1 = bev.y - mnv.y * sc1;
    float sc2 = gav.z * rsqrtf(vrv.z + 1e-5f), sh2 = bev.z - mnv.z * sc2;
    float sc3 = gav.w * rsqrtf(vrv.w + 1e-5f), sh3 = bev.w - mnv.w * sc3;
    int P = (N + 1) >> 1;
    for (int p = blockIdx.x * wpb + wave; p < P; p += gridDim.x * wpb) {
        int d0  = p << 1;
        int d1  = d0 + 1;
        int rs0 = row_start[d0];
        int re0 = row_start[d0 + 1];
        int deg0 = re0 - rs0;
        int deg1 = -1, re1 = 0;
        if (d1 < N) { re1 = row_start[d1 + 1]; deg1 = re1 - re0; }
        if (deg0 <= 32 && deg1 >= 0 && deg1 <= 32) {
            // ---- paired fast path ----
            int d   = half ? d1 : d0;
            int rs  = half ? re0 : rs0;
            int deg = half ? deg1 : deg0;
            float add = ad[d];
            int s = 0; float w = 0.f;
            if (l < deg) {
                s = csr_src[rs + l];
                float e = as[s] + add;
                e = (e > 0.f) ? e : 0.2f * e;
                w = __expf(fminf(e, 60.f));
            }
            swbuf[wave][lane] = make_float2(__int_as_float(s), w);
            float z = w;
#pragma unroll
            for (int o = 16; o > 0; o >>= 1) z += __shfl_xor(z, o, 64);
            asm volatile("s_waitcnt lgkmcnt(0)" ::: "memory");
            int es = l >> 4;
            float a0 = 0.f, a1 = 0.f, a2 = 0.f, a3 = 0.f;
            int nb = (deg + 1) >> 1;
#pragma unroll 2
            for (int b = 0; b < nb; ++b) {
                int j  = (b << 1) + es;
                float2 sw = swbuf[wave][(half << 5) + j];  // 16-lane uniform -> bcast
                int   sj = __float_as_int(sw.x);
                float wj = sw.y;
                const __half2* hp = reinterpret_cast<const __half2*>(h16 + (size_t)sj * 64 + cg);
                float2 f0 = __half22float2(hp[0]);
                float2 f1 = __half22float2(hp[1]);
                a0 = fmaf(f0.x, wj, a0);
                a1 = fmaf(f0.y, wj, a1);
                a2 = fmaf(f1.x, wj, a2);
                a3 = fmaf(f1.y, wj, a3);
            }
            a0 += __shfl_xor(a0, 16, 64);
            a1 += __shfl_xor(a1, 16, 64);
            a2 += __shfl_xor(a2, 16, 64);
            a3 += __shfl_xor(a3, 16, 64);
            if (es == 0) {
                float rz = 1.f / z;
                float o0 = fmaxf(fmaf(a0, rz, bcv.x), 0.f);
                float o1 = fmaxf(fmaf(a1, rz, bcv.y), 0.f);
                float o2 = fmaxf(fmaf(a2, rz, bcv.z), 0.f);
                float o3 = fmaxf(fmaf(a3, rz, bcv.w), 0.f);
                union { __half2 h2[2]; uint2 u; } pk;
                pk.h2[0] = __floats2half2_rn(fmaf(o0, sc0, sh0), fmaf(o1, sc1, sh1));
                pk.h2[1] = __floats2half2_rn(fmaf(o2, sc2, sh2), fmaf(o3, sc3, sh3));
                *reinterpret_cast<uint2*>(&xout[(size_t)d * 64 + cg]) = pk.u;
            }
        } else {
            // ---- per-node paths (rare) ----
            for (int k = 0; k < 2; ++k) {
                int d = d0 + k;
                if (d >= N) break;
                int rs  = row_start[d], re = row_start[d + 1];
                int deg = re - rs;
                float add = ad[d];
                if (deg <= 64) {
                    int s = 0; float w = 0.f;
                    if (lane < deg) {
                        s = csr_src[rs + lane];
                        float e = as[s] + add;
                        e = (e > 0.f) ? e : 0.2f * e;
                        w = __expf(fminf(e, 60.f));
                    }
                    float z = w;
#pragma unroll
                    for (int o = 32; o > 0; o >>= 1) z += __shfl_xor(z, o, 64);
                    int es4 = lane >> 4;
                    float a0 = 0.f, a1 = 0.f, a2 = 0.f, a3 = 0.f;
                    int nb = (deg + 3) >> 2;
                    for (int b = 0; b < nb; ++b) {
                        int j = (b << 2) + es4;
                        int   sj = __shfl(s, j, 64);
                        float wj = __shfl(w, j, 64);
                        const __half2* hp = reinterpret_cast<const __half2*>(h16 + (size_t)sj * 64 + cg);
                        float2 f0 = __half22float2(hp[0]);
                        float2 f1 = __half22float2(hp[1]);
                        a0 = fmaf(f0.x, wj, a0);
                        a1 = fmaf(f0.y, wj, a1);
                        a2 = fmaf(f1.x, wj, a2);
                        a3 = fmaf(f1.y, wj, a3);
                    }
                    a0 += __shfl_xor(a0, 16, 64); a0 += __shfl_xor(a0, 32, 64);
                    a1 += __shfl_xor(a1, 16, 64); a1 += __shfl_xor(a1, 32, 64);
                    a2 += __shfl_xor(a2, 16, 64); a2 += __shfl_xor(a2, 32, 64);
                    a3 += __shfl_xor(a3, 16, 64); a3 += __shfl_xor(a3, 32, 64);
                    if (lane < 16) {
                        float rz = 1.f / z;
                        float o0 = fmaxf(fmaf(a0, rz, bcv.x), 0.f);
                        float o1 = fmaxf(fmaf(a1, rz, bcv.y), 0.f);
                        float o2 = fmaxf(fmaf(a2, rz, bcv.z), 0.f);
                        float o3 = fmaxf(fmaf(a3, rz, bcv.w), 0.f);
                        union { __half2 h2[2]; uint2 u; } pk;
                        pk.h2[0] = __floats2half2_rn(fmaf(o0, sc0, sh0), fmaf(o1, sc1, sh1));
                        pk.h2[1] = __floats2half2_rn(fmaf(o2, sc2, sh2), fmaf(o3, sc3, sh3));
                        *reinterpret_cast<uint2*>(&xout[(size_t)d * 64 + cg]) = pk.u;
                    }
                } else {  // deg > 64: serial, lane = channel
                    float z = 0.f;
                    for (int j = rs + lane; j < re; j += 64) {
                        float e = as[csr_src[j]] + add;
                        e = (e > 0.f) ? e : 0.2f * e;
                        z += __expf(fminf(e, 60.f));
                    }
#pragma unroll
                    for (int o = 32; o > 0; o >>= 1) z += __shfl_xor(z, o, 64);
                    float acc = 0.f;
                    for (int j = rs; j < re; ++j) {
                        int si = csr_src[j];
                        float e = as[si] + add;
                        e = (e > 0.f) ? e : 0.2f * e;
                        float w = __expf(fminf(e, 60.f));
                        acc = fmaf(__half2float(h16[(size_t)si * 64 + lane]), w, acc);
                    }
                    float scl = gamma[lane] * rsqrtf(var[lane] + 1e-5f);
                    float shf = beta[lane] - mean[lane] * scl;
                    float o = fmaxf(acc / z + bias[lane], 0.f);
                    xout[(size_t)d * 64 + lane] = __float2half(fmaf(o, scl, shf));
                }
            }
        }
    }
}

// Pool: block g binary-searches sorted batch for its node range; x is fp16.
__global__ __launch_bounds__(256) void pool_kernel(const __half* __restrict__ x16,
                                                   const int* __restrict__ batch,
                                                   const float* __restrict__ Wr,
                                                   const float* __restrict__ br,
                                                   float* __restrict__ out, int N, int G) {
    __shared__ float wsum[4][64];
    __shared__ int bounds[2];
    int t    = threadIdx.x;
    int lane = t & 63;
    int wv   = t >> 6;
    int g    = blockIdx.x;
    if (g >= G) return;
    if (t < 2) {
        int key = g + t;         // lower_bound(batch, key)
        int lo = 0, hi = N;
        while (lo < hi) {
            int mid = (lo + hi) >> 1;
            if (batch[mid] < key) lo = mid + 1; else hi = mid;
        }
        bounds[t] = lo;
    }
    __syncthreads();
    int s   = bounds[0];
    int cnt = bounds[1] - s;
    float a0 = 0.f, a1 = 0.f, a2 = 0.f, a3 = 0.f;
    for (int r = wv * 4; r < cnt; r += 16) {
        const __half* row = x16 + (size_t)(s + r) * 64 + lane;
        a0 += __half2float(row[0]);
        if (r + 1 < cnt) a1 += __half2float(row[64]);
        if (r + 2 < cnt) a2 += __half2float(row[128]);
        if (r + 3 < cnt) a3 += __half2float(row[192]);
    }
    wsum[wv][lane] = (a0 + a1) + (a2 + a3);
    __syncthreads();
    if (wv == 0) {
        float tot = (wsum[0][lane] + wsum[1][lane]) + (wsum[2][lane] + wsum[3][lane]);
        float pooled = tot / fmaxf((float)cnt, 1.f);
        out[G + (size_t)g * 64 + lane] = pooled;
        float p = pooled * Wr[lane];
#pragma unroll
        for (int o = 32; o > 0; o >>= 1) p += __shfl_xor(p, o, 64);
        if (lane == 0) out[g] = p + br[0];
    }
}

extern "C" void kernel_launch(void* const* d_in, const int* in_sizes, int n_in,
                              void* d_out, int out_size, void* d_ws, size_t ws_size,
                              hipStream_t stream) {
    const float* X        = (const float*)d_in[0];
    const int*   ei       = (const int*)d_in[1];
    const int*   batch    = (const int*)d_in[2];
    const float* W1       = (const float*)d_in[3];
    const float* Ws       = (const float*)d_in[4];
    const float* att_src  = (const float*)d_in[5];
    const float* att_dst  = (const float*)d_in[6];
    const float* bias     = (const float*)d_in[7];
    const float* bn_gamma = (const float*)d_in[8];
    const float* bn_beta  = (const float*)d_in[9];
    const float* bn_mean  = (const float*)d_in[10];
    const float* bn_var   = (const float*)d_in[11];
    const float* Wr       = (const float*)d_in[12];
    const float* br       = (const float*)d_in[13];

    const int N = in_sizes[0];        // IN == 1
    const int E = in_sizes[1] / 2;
    const int G = out_size / 65;      // pred[G] + pooled[G*64]
    const int T = E + N;
    const int NB = (N + 255) >> 8;    // dst buckets (196 for N=50000; <=256)

    char* ws = (char*)d_ws;
    size_t off = 0;
    auto take = [&](size_t bytes) {
        void* p = ws + off;
        off = (off + bytes + 255) & ~(size_t)255;
        return p;
    };
    int*      row_start  = (int*)take(sizeof(int) * (N + 1));
    int*      csr_src    = (int*)take(sizeof(int) * T);
    float*    as         = (float*)take(sizeof(float) * N);
    float*    ad         = (float*)take(sizeof(float) * N);
    __half*   h16        = (__half*)take(sizeof(__half) * (size_t)N * 64);
    __half*   xa         = (__half*)take(sizeof(__half) * (size_t)N * 64);
    __half*   xb         = (__half*)take(sizeof(__half) * (size_t)N * 64);
    int*      bkt_cursor = (int*)take(sizeof(int) * NB);
    unsigned* ebuf       = (unsigned*)take(sizeof(unsigned) * (size_t)NB * BCAP);
    (void)ws_size;

    const int* esrc = ei;
    const int* edst = ei + E;

    hipMemsetAsync(bkt_cursor, 0, sizeof(int) * NB, stream);

    bucket_scatter_kernel<<<(T + CH - 1) / CH, 256, 0, stream>>>(esrc, edst, bkt_cursor,
                                                                 ebuf, E, N, NB);
    bucket_sort_kernel<<<NB, 256, 0, stream>>>(ebuf, bkt_cursor, row_start, csr_src,
                                               X, W1, att_src, att_dst,
                                               bias, bn_gamma, bn_beta, bn_mean, bn_var,
                                               xa, N, NB);

    int tb   = (N + 63) / 64;           // transform: 64-node tiles
    int P    = (N + 1) / 2;
    int wb2  = (P + 3) / 4;             // aggregate: 2 nodes/wave
    __half* xin = xa;
    __half* xout = xb;
    for (int L = 1; L < 5; ++L) {
        transform_kernel<<<tb, 256, 0, stream>>>(xin, Ws + (size_t)(L - 1) * 64 * 64,
                                                 att_src + (size_t)L * 64, att_dst + (size_t)L * 64,
                                                 h16, as, ad, N);
        aggregate_kernel<<<wb2, 256, 0, stream>>>(h16, as, ad, row_start, csr_src,
                                                  bias + (size_t)L * 64, bn_gamma + (size_t)L * 64,
                                                  bn_beta + (size_t)L * 64, bn_mean + (size_t)L * 64,
                                                  bn_var + (size_t)L * 64, xout, N);
        __half* t = xin; xin = xout; xout = t;
    }

    pool_kernel<<<G, 256, 0, stream>>>(xin, batch, Wr, br, (float*)d_out, N, G);
}